// Round 3
// baseline (162.044 us; speedup 1.0000x reference)
//
#include <hip/hip_runtime.h>

// InvertAffine: per sample, full = [[I+M, t],[0,1]] (4x4). Inverse is
// [[B, -B t],[0,1]] with B = (I+M)^{-1} via 3x3 cofactors.
// 192 MB logical traffic; write-only fill ~6.7 TB/s; float4 copy 6.29 TB/s.
//
// R1/R2: coalescing, LDS staging, streaming shape, occupancy all neutral.
// R3/R5: NT stores neutral (RFO theory dead).
// R6: NT loads WIN (-7us): read-allocation was evicting dirty poison lines.
// R7: wave-private LDS, no s_barrier, 2 samples/thread -> NEUTRAL.
//     Falsifies barrier-drain + per-wave-MLP theories.
// R8 theory: one-shot blocks create per-CU read-convoy/write-convoy
//     alternation + 3907 short-lived blocks (launch/drain tails). Copy
//     benchmarks that hit 6.29 TB/s are persistent grid-stride loops with
//     both streams continuously in flight. Fix: persistent kernel, 2048
//     blocks (8/CU, 32 waves/CU), 1-deep software pipeline: NT loads for
//     tile t+stride issued before compute of tile t, waited (counted
//     vmcnt) only at the next iteration's LDS write. Wave-private LDS,
//     zero s_barriers, NT both directions.

typedef float nfloat4 __attribute__((ext_vector_type(4)));

__global__ __launch_bounds__(256, 8) void invert_affine_kernel(
    const float4* __restrict__ in, float4* __restrict__ out, int b) {
  __shared__ float4 buf[4][192];  // per-wave: 64 samples * 3 float4 = 3 KB

  const int wave = threadIdx.x >> 6;
  const int lane = threadIdx.x & 63;
  float4* wbuf = buf[wave];

  const int n_f4 = b * 3;
  const int ntiles = (b + 255) >> 8;   // 256-sample block tiles
  const int gstride = (int)gridDim.x;

  int it = (int)blockIdx.x;
  if (it >= ntiles) return;

  // prologue: NT-load tile `it` into regs
  nfloat4 r0 = {0.f, 0.f, 0.f, 0.f}, r1 = r0, r2 = r0;
  {
    const int base = (it * 256 + wave * 64) * 3 + lane;
    if (base < n_f4)
      r0 = __builtin_nontemporal_load((const nfloat4*)&in[base]);
    if (base + 64 < n_f4)
      r1 = __builtin_nontemporal_load((const nfloat4*)&in[base + 64]);
    if (base + 128 < n_f4)
      r2 = __builtin_nontemporal_load((const nfloat4*)&in[base + 128]);
  }

  while (true) {
    // regs -> wave-local LDS (dense). Compiler inserts counted vmcnt waits
    // for r0..r2 here; previous iteration's stores stay in flight.
    wbuf[lane]       = make_float4(r0.x, r0.y, r0.z, r0.w);
    wbuf[64 + lane]  = make_float4(r1.x, r1.y, r1.z, r1.w);
    wbuf[128 + lane] = make_float4(r2.x, r2.y, r2.z, r2.w);
    __builtin_amdgcn_wave_barrier();

    const int nxt = it + gstride;
    // issue NT loads for the next tile NOW: they stay in flight across the
    // whole compute + store phase below (read & write streams overlap).
    if (nxt < ntiles) {
      const int base = (nxt * 256 + wave * 64) * 3 + lane;
      if (base < n_f4)
        r0 = __builtin_nontemporal_load((const nfloat4*)&in[base]);
      if (base + 64 < n_f4)
        r1 = __builtin_nontemporal_load((const nfloat4*)&in[base + 64]);
      if (base + 128 < n_f4)
        r2 = __builtin_nontemporal_load((const nfloat4*)&in[base + 128]);
    }

    // compute tile `it` from LDS (wave-local ordering, stride-48B reads:
    // same bank-quad distribution as dense -> conflict-free)
    const int s = it * 256 + wave * 64 + lane;
    if (s < b) {
      const int o = lane * 3;
      float4 q0 = wbuf[o + 0];
      float4 q1 = wbuf[o + 1];
      float4 q2 = wbuf[o + 2];

      float a00 = q0.x + 1.0f, a01 = q0.y,        a02 = q0.z,        t0 = q0.w;
      float a10 = q1.x,        a11 = q1.y + 1.0f, a12 = q1.z,        t1 = q1.w;
      float a20 = q2.x,        a21 = q2.y,        a22 = q2.z + 1.0f, t2 = q2.w;

      float b00 = a11 * a22 - a12 * a21;
      float b01 = a02 * a21 - a01 * a22;
      float b02 = a01 * a12 - a02 * a11;
      float b10 = a12 * a20 - a10 * a22;
      float b11 = a00 * a22 - a02 * a20;
      float b12 = a02 * a10 - a00 * a12;
      float b20 = a10 * a21 - a11 * a20;
      float b21 = a01 * a20 - a00 * a21;
      float b22 = a00 * a11 - a01 * a10;

      float det = a00 * b00 + a01 * b10 + a02 * b20;
      float rdet = 1.0f / det;

      b00 *= rdet; b01 *= rdet; b02 *= rdet;
      b10 *= rdet; b11 *= rdet; b12 *= rdet;
      b20 *= rdet; b21 *= rdet; b22 *= rdet;

      wbuf[o + 0] = make_float4(b00 - 1.0f, b01, b02,
                                -(b00 * t0 + b01 * t1 + b02 * t2));
      wbuf[o + 1] = make_float4(b10, b11 - 1.0f, b12,
                                -(b10 * t0 + b11 * t1 + b12 * t2));
      wbuf[o + 2] = make_float4(b20, b21, b22 - 1.0f,
                                -(b20 * t0 + b21 * t1 + b22 * t2));
    }
    __builtin_amdgcn_wave_barrier();

    // dense wave-local LDS -> NT store (overlaps the in-flight next loads)
    {
      const int base = (it * 256 + wave * 64) * 3 + lane;
      if (base < n_f4) {
        float4 v = wbuf[lane];
        nfloat4 nv; nv.x = v.x; nv.y = v.y; nv.z = v.z; nv.w = v.w;
        __builtin_nontemporal_store(nv, (nfloat4*)&out[base]);
      }
      if (base + 64 < n_f4) {
        float4 v = wbuf[64 + lane];
        nfloat4 nv; nv.x = v.x; nv.y = v.y; nv.z = v.z; nv.w = v.w;
        __builtin_nontemporal_store(nv, (nfloat4*)&out[base + 64]);
      }
      if (base + 128 < n_f4) {
        float4 v = wbuf[128 + lane];
        nfloat4 nv; nv.x = v.x; nv.y = v.y; nv.z = v.z; nv.w = v.w;
        __builtin_nontemporal_store(nv, (nfloat4*)&out[base + 128]);
      }
    }
    __builtin_amdgcn_wave_barrier();

    if (nxt >= ntiles) break;
    it = nxt;
  }
}

extern "C" void kernel_launch(void* const* d_in, const int* in_sizes, int n_in,
                              void* d_out, int out_size, void* d_ws, size_t ws_size,
                              hipStream_t stream) {
  const float4* trf = (const float4*)d_in[0];
  float4* out = (float4*)d_out;
  int b = in_sizes[0] / 12;  // 2,000,000 samples
  const int threads = 256;
  int blocks = 2048;         // persistent: 8 blocks/CU * 256 CUs
  const int ntiles = (b + 255) >> 8;
  if (blocks > ntiles) blocks = ntiles;
  invert_affine_kernel<<<blocks, threads, 0, stream>>>(trf, out, b);
}